// Round 27
// baseline (352.436 us; speedup 1.0000x reference)
//
#include <hip/hip_runtime.h>

#define BTOT 65536
#define TST  28
#define PACK_DW 100
// ws layout (dwords): [0 .. 12800) packed frags (2 p-variants x 64 lanes x 100)
//                     [12800 .. 16896) WxL: 32 x 128 f32 (rows 29..31 zeroed)
#define WXL_OFF 12800

typedef __attribute__((ext_vector_type(8))) short bf16x8;
typedef __attribute__((ext_vector_type(4))) float f32x4;
typedef __attribute__((ext_vector_type(4))) unsigned int u32x4;

__device__ __forceinline__ unsigned int f2bf(float f) {
    unsigned u = __float_as_uint(f);
    u += 0x7fff + ((u >> 16) & 1);   // RNE
    return u >> 16;
}
__device__ __forceinline__ unsigned int pk2bf(float a, float b) {
    return f2bf(a) | (f2bf(b) << 16);
}
__device__ __forceinline__ bf16x8 cvt8(f32x4 a, f32x4 b) {
    union { unsigned int u[4]; bf16x8 v; } r;
    asm("v_cvt_pk_bf16_f32 %0, %1, %2" : "=v"(r.u[0]) : "v"(a[0]), "v"(a[1]));
    asm("v_cvt_pk_bf16_f32 %0, %1, %2" : "=v"(r.u[1]) : "v"(a[2]), "v"(a[3]));
    asm("v_cvt_pk_bf16_f32 %0, %1, %2" : "=v"(r.u[2]) : "v"(b[0]), "v"(b[1]));
    asm("v_cvt_pk_bf16_f32 %0, %1, %2" : "=v"(r.u[3]) : "v"(b[2]), "v"(b[3]));
    return r.v;
}

// sigma (r23-verified): B-frag slot (kh,kk,jd,b) consumes h-unit
// s = kk*32 + (jd>>1)*16 + kh*4 + (jd&1)*2 + b. CVT of global acc tile T8
// lands in hb[T8>>1].u[(T8&1)*2 .. +1] — register-only feedback for the
// wave's OWN kk pair; partner's pair crosses LDS (2 b128 each way + 1 barrier).

// pack1: blocks 0..28 compute WxL row k (Wx = W1@W2a; row 28 = b2 + b1@W2a,
// hit by x-frag col 28 := 1.0; block 28 zeroes rows 29..31). Block 29 packs
// sigma-permuted W2b A-frags for both p-halves (kk = ALL 4, n restricted to
// the half); block 30 packs sigma W3 frags + b3 (p=0 only — epilogue wave).
__global__ void pack1(const float* __restrict__ W1, const float* __restrict__ b1,
                      const float* __restrict__ W2, const float* __restrict__ b2,
                      const float* __restrict__ W3, const float* __restrict__ b3,
                      unsigned int* __restrict__ ws) {
    float* WxL = (float*)(ws + WXL_OFF);
    const int bid = blockIdx.x, tid = threadIdx.x;
    if (bid < 29) {
        const int k = bid, n = tid;   // 128 threads
        float s = 0.f;
        if (k < 28) {
            for (int m = 0; m < 128; ++m) s += W1[k * 128 + m] * W2[m * 128 + n];
        } else {
            s = b2[n];
            for (int m = 0; m < 128; ++m) s += b1[m] * W2[m * 128 + n];
        }
        WxL[k * 128 + n] = s;
        if (k == 28) { WxL[29*128+n] = 0.f; WxL[30*128+n] = 0.f; WxL[31*128+n] = 0.f; }
    } else if (bid == 29) {
        if (tid < 64) {
            const int lr = tid & 15, kh = tid >> 4;
            for (int p = 0; p < 2; ++p) {
                unsigned int* P = ws + (p * 64 + tid) * PACK_DW;
                for (int kk = 0; kk < 4; ++kk)
                    for (int t4 = 0; t4 < 4; ++t4)
                        for (int jd = 0; jd < 4; ++jd) {
                            const int s = kk * 32 + (jd >> 1) * 16 + kh * 4 + (jd & 1) * 2;
                            const int n = p * 64 + t4 * 16 + lr;
                            P[(kk * 4 + t4) * 4 + jd] =
                                pk2bf(W2[(128 + s) * 128 + n], W2[(129 + s) * 128 + n]);
                        }
            }
        }
    } else {
        if (tid < 64) {
            const int lr = tid & 15, kh = tid >> 4;
            unsigned int* P = ws + tid * PACK_DW;   // p=0 rows only
            for (int kk = 0; kk < 4; ++kk)
                for (int jd = 0; jd < 4; ++jd) {
                    const int s = kk * 32 + (jd >> 1) * 16 + kh * 4 + (jd & 1) * 2;
                    float lo = (lr < 10) ? W3[s * 10 + lr] : 0.f;
                    float hi = (lr < 10) ? W3[(s + 1) * 10 + lr] : 0.f;
                    P[80 + kk * 4 + jd] = pk2bf(lo, hi);
                }
            for (int j = 0; j < 4; ++j) {
                const int o = kh * 4 + j;
                P[96 + j] = __float_as_uint((o < 10) ? b3[o] : 0.f);
            }
        }
    }
}

// pack2: wx A-frags (natural k order; n restricted per half).
__global__ void pack2(unsigned int* __restrict__ ws) {
    const int tid = threadIdx.x;
    if (tid < 64) {
        const float* WxL = (const float*)(ws + WXL_OFF);
        const int lr = tid & 15, kh = tid >> 4;
        for (int p = 0; p < 2; ++p) {
            unsigned int* P = ws + (p * 64 + tid) * PACK_DW;
            for (int t4 = 0; t4 < 4; ++t4)
                for (int jd = 0; jd < 4; ++jd) {
                    const int k = kh * 8 + jd * 2, n = p * 64 + t4 * 16 + lr;
                    P[64 + t4 * 4 + jd] = pk2bf(WxL[k * 128 + n], WxL[(k + 1) * 128 + n]);
                }
        }
    }
}

#define MFMA(a, b, c) __builtin_amdgcn_mfma_f32_16x16x32_bf16(a, b, c, 0, 0, 0)

// n-split + sigma hybrid: block = 2 waves (1 team, 16 batch rows); wave p owns
// cols [64p, 64p+64) = global tiles 4p..4p+3 -> produces hb frags kk=2p,2p+1
// REGISTER-ONLY (sigma). Partner's 2 frags cross LDS: 2 b128 writes + 2 b128
// reads + ONE raw lgkm barrier per step. ~145 VGPR -> 3 waves/SIMD (1.5x the
// r23 residency) with 20 MFMA/wave-step.
__global__ __launch_bounds__(128, 3) void rnn_kernel(
    const float* __restrict__ x, const unsigned int* __restrict__ wsPack,
    float* __restrict__ out)
{
    __shared__ __align__(16) unsigned int Hs[2][4][256];   // [buf][kk][lane*4]: 8KB
    const int tid = threadIdx.x;
    const int p = tid >> 6, lane = tid & 63, lr = lane & 15, kh = lane >> 4;
    const int r0 = blockIdx.x * 16;
    const int kkO = 2 * p;            // own kk pair: kkO, kkO+1
    const int kkP = 2 * (1 - p);      // partner pair: kkP, kkP+1

    const unsigned int* P = wsPack + (p * 64 + lane) * PACK_DW;
    bf16x8 w2b[4][4], wx[4];
    #pragma unroll
    for (int kk = 0; kk < 4; ++kk)
        #pragma unroll
        for (int t4 = 0; t4 < 4; ++t4)
            w2b[kk][t4] = *(const bf16x8*)(P + (kk * 4 + t4) * 4);
    #pragma unroll
    for (int t4 = 0; t4 < 4; ++t4) wx[t4] = *(const bf16x8*)(P + 64 + t4 * 4);

    // x B-frag: lane (kh,lr) covers k = 8kh + j of x[r0+lr][28t + k];
    // kh==3 upper half = {1.0 (col-28 bias hook), 0,0,0} — Wx rows 29..31 zero.
    const f32x4 onec = {1.f, 0.f, 0.f, 0.f};
    const float* xr = x + (size_t)(r0 + lr) * 784 + 8 * kh;
    f32x4 xa = *(const f32x4*)xr;
    f32x4 xc = (kh < 3) ? *(const f32x4*)(xr + 4) : onec;
    bf16x8 xb = cvt8(xa, xc);
    const f32x4 z4 = {0.f, 0.f, 0.f, 0.f};

    f32x4 acc[4];
    union HF { unsigned int u[4]; bf16x8 v; } hbO[2];
    f32x4 na, nc;

// CVT own tile T4 (global T8 = 4p+T4) -> hbO[T4>>1].u[(T4&1)*2 .. +1]
#define CVT(T4) do {                                                        \
        f32x4 v = acc[T4];                                                  \
        v[0] = fmaxf(v[0], 0.f); v[1] = fmaxf(v[1], 0.f);                   \
        v[2] = fmaxf(v[2], 0.f); v[3] = fmaxf(v[3], 0.f);                   \
        unsigned lo, hi;                                                    \
        asm("v_cvt_pk_bf16_f32 %0, %1, %2" : "=v"(lo) : "v"(v[0]), "v"(v[1])); \
        asm("v_cvt_pk_bf16_f32 %0, %1, %2" : "=v"(hi) : "v"(v[2]), "v"(v[3])); \
        hbO[(T4) >> 1].u[((T4) & 1) * 2]     = lo;                          \
        hbO[(T4) >> 1].u[((T4) & 1) * 2 + 1] = hi;                          \
    } while (0)
#define CVTALL  CVT(0); CVT(1); CVT(2); CVT(3)
// write own frags to exchange buf B (b128, lane-linear -> conflict-free)
#define XWRITE(B) do {                                                      \
        *(u32x4*)&Hs[B][kkO][lane * 4]     = *(const u32x4*)hbO[0].u;       \
        *(u32x4*)&Hs[B][kkO + 1][lane * 4] = *(const u32x4*)hbO[1].u;       \
    } while (0)
#define BAR asm volatile("s_waitcnt lgkmcnt(0)\n\ts_barrier" ::: "memory")

    int cur = 0;
    // ---- step 0: h0 == 0, x part only (exact) ----
    {
        const float* xp = xr + 28;
        na = *(const f32x4*)xp;
        nc = (kh < 3) ? *(const f32x4*)(xp + 4) : onec;
        #pragma unroll
        for (int t4 = 0; t4 < 4; ++t4)
            acc[t4] = MFMA(wx[t4], xb, z4);
        xb = cvt8(na, nc);
        CVTALL;
        XWRITE(0);
        BAR;
    }

    // ---- steps 1..27 ----
    #pragma unroll 2
    for (int t = 1; t < TST; ++t) {
        // partner frags for h_t (written before the last barrier)
        bf16x8 hbP0 = *(const bf16x8*)&Hs[cur][kkP][lane * 4];
        bf16x8 hbP1 = *(const bf16x8*)&Hs[cur][kkP + 1][lane * 4];
        const bool pf = (t + 1 < TST);
        if (pf) {
            const float* xp = xr + (t + 1) * 28;
            na = *(const f32x4*)xp;
            nc = (kh < 3) ? *(const f32x4*)(xp + 4) : onec;
        }
        __builtin_amdgcn_s_setprio(1);
        // x-part + own-h first (covers the partner-read latency)
        #pragma unroll
        for (int t4 = 0; t4 < 4; ++t4)
            acc[t4] = MFMA(wx[t4], xb, z4);
        #pragma unroll
        for (int i = 0; i < 2; ++i)
            #pragma unroll
            for (int t4 = 0; t4 < 4; ++t4)
                acc[t4] = MFMA(w2b[kkO + i][t4], hbO[i].v, acc[t4]);
        // partner-h
        #pragma unroll
        for (int t4 = 0; t4 < 4; ++t4)
            acc[t4] = MFMA(w2b[kkP][t4], hbP0, acc[t4]);
        #pragma unroll
        for (int t4 = 0; t4 < 4; ++t4)
            acc[t4] = MFMA(w2b[kkP + 1][t4], hbP1, acc[t4]);
        __builtin_amdgcn_s_setprio(0);
        if (pf) xb = cvt8(na, nc);
        CVTALL;              // hbO now holds h_{t+1} own frags (register-only)
        XWRITE(cur ^ 1);     // publish for partner
        BAR;
        cur ^= 1;
    }

    // epilogue: p==0 computes out^T = W3^T.h_final^T + b3 (own frags in regs,
    // partner frags in Hs[cur] from the final exchange)
    if (p == 0) {
        bf16x8 hbP0 = *(const bf16x8*)&Hs[cur][kkP][lane * 4];
        bf16x8 hbP1 = *(const bf16x8*)&Hs[cur][kkP + 1][lane * 4];
        bf16x8 w3f[4];
        #pragma unroll
        for (int kk = 0; kk < 4; ++kk) w3f[kk] = *(const bf16x8*)(P + 80 + kk * 4);
        const float* bp = (const float*)(P + 96);
        f32x4 accO = {bp[0], bp[1], bp[2], bp[3]};
        accO = MFMA(w3f[kkO],     hbO[0].v, accO);
        accO = MFMA(w3f[kkO + 1], hbO[1].v, accO);
        accO = MFMA(w3f[kkP],     hbP0,     accO);
        accO = MFMA(w3f[kkP + 1], hbP1,     accO);
        float* op = out + (size_t)(r0 + lr) * 10 + kh * 4;
        #pragma unroll
        for (int j = 0; j < 4; ++j)
            if (kh * 4 + j < 10) op[j] = accO[j];
    }

#undef CVT
#undef CVTALL
#undef XWRITE
#undef BAR
}

extern "C" void kernel_launch(void* const* d_in, const int* in_sizes, int n_in,
                              void* d_out, int out_size, void* d_ws, size_t ws_size,
                              hipStream_t stream) {
    const float* x  = (const float*)d_in[0];
    const float* W1 = (const float*)d_in[1];
    const float* b1 = (const float*)d_in[2];
    const float* W2 = (const float*)d_in[3];
    const float* b2 = (const float*)d_in[4];
    const float* W3 = (const float*)d_in[5];
    const float* b3 = (const float*)d_in[6];
    unsigned int* ws = (unsigned int*)d_ws;   // 16896 dwords = 66 KiB

    pack1<<<31, 128, 0, stream>>>(W1, b1, W2, b2, W3, b3, ws);
    pack2<<<1, 64, 0, stream>>>(ws);
    rnn_kernel<<<BTOT / 16, 128, 0, stream>>>(x, ws, (float*)d_out);
}

// Round 28
// 78.573 us; speedup vs baseline: 4.4854x; 4.4854x over previous
//
#include <hip/hip_runtime.h>

#define BTOT 65536
#define TST  28
#define PACK_DW 100
// ws layout (dwords): [0 .. 12800) packed frags (2 p-variants x 64 lanes x 100)
//                     [12800 .. 16896) WxL: 32 x 128 f32 (rows 29..31 zeroed)
#define WXL_OFF 12800

typedef __attribute__((ext_vector_type(8))) short bf16x8;
typedef __attribute__((ext_vector_type(4))) float f32x4;
typedef __attribute__((ext_vector_type(4))) unsigned int u32x4;

__device__ __forceinline__ unsigned int f2bf(float f) {
    unsigned u = __float_as_uint(f);
    u += 0x7fff + ((u >> 16) & 1);   // RNE
    return u >> 16;
}
__device__ __forceinline__ unsigned int pk2bf(float a, float b) {
    return f2bf(a) | (f2bf(b) << 16);
}
__device__ __forceinline__ bf16x8 cvt8(f32x4 a, f32x4 b) {
    union { unsigned int u[4]; bf16x8 v; } r;
    asm("v_cvt_pk_bf16_f32 %0, %1, %2" : "=v"(r.u[0]) : "v"(a[0]), "v"(a[1]));
    asm("v_cvt_pk_bf16_f32 %0, %1, %2" : "=v"(r.u[1]) : "v"(a[2]), "v"(a[3]));
    asm("v_cvt_pk_bf16_f32 %0, %1, %2" : "=v"(r.u[2]) : "v"(b[0]), "v"(b[1]));
    asm("v_cvt_pk_bf16_f32 %0, %1, %2" : "=v"(r.u[3]) : "v"(b[2]), "v"(b[3]));
    return r.v;
}

// sigma (r23-verified): B-frag slot (kh,kk,jd,b) consumes h-unit
// s = kk*32 + (jd>>1)*16 + kh*4 + (jd&1)*2 + b.
//
// r27 POST-MORTEM FIX (rule #20): w2b was indexed with RUNTIME kkO/kkP ->
// whole array spilled to scratch (FETCH 964MB, 352us). Now the p-dependence
// is folded into PACKING: for variant p, slot i = global kk (i ^ 2p), so
// slots 0,1 are always the wave's OWN pair and 2,3 the PARTNER pair — all
// register-array indices in the kernel are compile-time constants.

// pack1: blocks 0..28 compute WxL row k (Wx = W1@W2a; row 28 = b2 + b1@W2a,
// hit by x-frag col 28 := 1.0; block 28 zeroes rows 29..31). Block 29 packs
// sigma-permuted W2b A-frags, slot-reordered per variant p (slot i -> global
// kk = i ^ 2p, n restricted to the half). Block 30 packs sigma W3 frags + b3
// (p=0 only — epilogue wave; for p=0 slot order == global order).
__global__ void pack1(const float* __restrict__ W1, const float* __restrict__ b1,
                      const float* __restrict__ W2, const float* __restrict__ b2,
                      const float* __restrict__ W3, const float* __restrict__ b3,
                      unsigned int* __restrict__ ws) {
    float* WxL = (float*)(ws + WXL_OFF);
    const int bid = blockIdx.x, tid = threadIdx.x;
    if (bid < 29) {
        const int k = bid, n = tid;   // 128 threads
        float s = 0.f;
        if (k < 28) {
            for (int m = 0; m < 128; ++m) s += W1[k * 128 + m] * W2[m * 128 + n];
        } else {
            s = b2[n];
            for (int m = 0; m < 128; ++m) s += b1[m] * W2[m * 128 + n];
        }
        WxL[k * 128 + n] = s;
        if (k == 28) { WxL[29*128+n] = 0.f; WxL[30*128+n] = 0.f; WxL[31*128+n] = 0.f; }
    } else if (bid == 29) {
        if (tid < 64) {
            const int lr = tid & 15, kh = tid >> 4;
            for (int p = 0; p < 2; ++p) {
                unsigned int* P = ws + (p * 64 + tid) * PACK_DW;
                for (int slot = 0; slot < 4; ++slot) {
                    const int gkk = slot ^ (2 * p);   // own pair in slots 0,1
                    for (int t4 = 0; t4 < 4; ++t4)
                        for (int jd = 0; jd < 4; ++jd) {
                            const int s = gkk * 32 + (jd >> 1) * 16 + kh * 4 + (jd & 1) * 2;
                            const int n = p * 64 + t4 * 16 + lr;
                            P[(slot * 4 + t4) * 4 + jd] =
                                pk2bf(W2[(128 + s) * 128 + n], W2[(129 + s) * 128 + n]);
                        }
                }
            }
        }
    } else {
        if (tid < 64) {
            const int lr = tid & 15, kh = tid >> 4;
            unsigned int* P = ws + tid * PACK_DW;   // p=0 rows only
            for (int kk = 0; kk < 4; ++kk)
                for (int jd = 0; jd < 4; ++jd) {
                    const int s = kk * 32 + (jd >> 1) * 16 + kh * 4 + (jd & 1) * 2;
                    float lo = (lr < 10) ? W3[s * 10 + lr] : 0.f;
                    float hi = (lr < 10) ? W3[(s + 1) * 10 + lr] : 0.f;
                    P[80 + kk * 4 + jd] = pk2bf(lo, hi);
                }
            for (int j = 0; j < 4; ++j) {
                const int o = kh * 4 + j;
                P[96 + j] = __float_as_uint((o < 10) ? b3[o] : 0.f);
            }
        }
    }
}

// pack2: wx A-frags (natural k order; n restricted per half).
__global__ void pack2(unsigned int* __restrict__ ws) {
    const int tid = threadIdx.x;
    if (tid < 64) {
        const float* WxL = (const float*)(ws + WXL_OFF);
        const int lr = tid & 15, kh = tid >> 4;
        for (int p = 0; p < 2; ++p) {
            unsigned int* P = ws + (p * 64 + tid) * PACK_DW;
            for (int t4 = 0; t4 < 4; ++t4)
                for (int jd = 0; jd < 4; ++jd) {
                    const int k = kh * 8 + jd * 2, n = p * 64 + t4 * 16 + lr;
                    P[64 + t4 * 4 + jd] = pk2bf(WxL[k * 128 + n], WxL[(k + 1) * 128 + n]);
                }
        }
    }
}

#define MFMA(a, b, c) __builtin_amdgcn_mfma_f32_16x16x32_bf16(a, b, c, 0, 0, 0)

// n-split + sigma hybrid (r27 intent, spill-fixed): block = 2 waves (1 team,
// 16 batch rows); wave p owns cols [64p,64p+64). Own hb pair register-only
// (sigma); partner pair crosses LDS (2 b128 writes + 2 b128 reads + ONE raw
// lgkm barrier/step). All register arrays statically indexed. ~145 VGPR ->
// 3 waves/SIMD at launch_bounds(128,3); 20 MFMA/wave-step.
__global__ __launch_bounds__(128, 3) void rnn_kernel(
    const float* __restrict__ x, const unsigned int* __restrict__ wsPack,
    float* __restrict__ out)
{
    __shared__ __align__(16) unsigned int Hs[2][4][256];   // [buf][kk][lane*4]: 8KB
    const int tid = threadIdx.x;
    const int p = tid >> 6, lane = tid & 63, lr = lane & 15, kh = lane >> 4;
    const int r0 = blockIdx.x * 16;
    const int kkO = 2 * p;            // own global pair (LDS addressing only)
    const int kkP = 2 - 2 * p;        // partner global pair (LDS addressing only)

    const unsigned int* P = wsPack + (p * 64 + lane) * PACK_DW;
    bf16x8 w2b[4][4], wx[4];          // w2b slots: 0,1 own; 2,3 partner
    #pragma unroll
    for (int slot = 0; slot < 4; ++slot)
        #pragma unroll
        for (int t4 = 0; t4 < 4; ++t4)
            w2b[slot][t4] = *(const bf16x8*)(P + (slot * 4 + t4) * 4);
    #pragma unroll
    for (int t4 = 0; t4 < 4; ++t4) wx[t4] = *(const bf16x8*)(P + 64 + t4 * 4);

    // x B-frag: lane (kh,lr) covers k = 8kh + j of x[r0+lr][28t + k];
    // kh==3 upper half = {1.0 (col-28 bias hook), 0,0,0} — Wx rows 29..31 zero.
    const f32x4 onec = {1.f, 0.f, 0.f, 0.f};
    const float* xr = x + (size_t)(r0 + lr) * 784 + 8 * kh;
    f32x4 xa = *(const f32x4*)xr;
    f32x4 xc = (kh < 3) ? *(const f32x4*)(xr + 4) : onec;
    bf16x8 xb = cvt8(xa, xc);
    const f32x4 z4 = {0.f, 0.f, 0.f, 0.f};

    f32x4 acc[4];
    union HF { unsigned int u[4]; bf16x8 v; } hbO[2];   // own pair, reg-only
    f32x4 na, nc;

// CVT own tile T4 (global T8 = 4p+T4) -> hbO[T4>>1].u[(T4&1)*2 .. +1]
#define CVT(T4) do {                                                        \
        f32x4 v = acc[T4];                                                  \
        v[0] = fmaxf(v[0], 0.f); v[1] = fmaxf(v[1], 0.f);                   \
        v[2] = fmaxf(v[2], 0.f); v[3] = fmaxf(v[3], 0.f);                   \
        unsigned lo, hi;                                                    \
        asm("v_cvt_pk_bf16_f32 %0, %1, %2" : "=v"(lo) : "v"(v[0]), "v"(v[1])); \
        asm("v_cvt_pk_bf16_f32 %0, %1, %2" : "=v"(hi) : "v"(v[2]), "v"(v[3])); \
        hbO[(T4) >> 1].u[((T4) & 1) * 2]     = lo;                          \
        hbO[(T4) >> 1].u[((T4) & 1) * 2 + 1] = hi;                          \
    } while (0)
#define CVTALL  CVT(0); CVT(1); CVT(2); CVT(3)
// write own frags to exchange buf B (b128, lane-linear -> conflict-free);
// kkO is a runtime LDS ADDRESS (legal) — not a register-array index.
#define XWRITE(B) do {                                                      \
        *(u32x4*)&Hs[B][kkO][lane * 4]     = *(const u32x4*)hbO[0].u;       \
        *(u32x4*)&Hs[B][kkO + 1][lane * 4] = *(const u32x4*)hbO[1].u;       \
    } while (0)
#define BAR asm volatile("s_waitcnt lgkmcnt(0)\n\ts_barrier" ::: "memory")

    int cur = 0;
    // ---- step 0: h0 == 0, x part only (exact) ----
    {
        const float* xp = xr + 28;
        na = *(const f32x4*)xp;
        nc = (kh < 3) ? *(const f32x4*)(xp + 4) : onec;
        #pragma unroll
        for (int t4 = 0; t4 < 4; ++t4)
            acc[t4] = MFMA(wx[t4], xb, z4);
        xb = cvt8(na, nc);
        CVTALL;
        XWRITE(0);
        BAR;
    }

    // ---- steps 1..27 ----
    #pragma unroll 2
    for (int t = 1; t < TST; ++t) {
        // partner frags for h_t (published before the last barrier)
        bf16x8 hbP0 = *(const bf16x8*)&Hs[cur][kkP][lane * 4];
        bf16x8 hbP1 = *(const bf16x8*)&Hs[cur][kkP + 1][lane * 4];
        const bool pf = (t + 1 < TST);
        if (pf) {
            const float* xp = xr + (t + 1) * 28;
            na = *(const f32x4*)xp;
            nc = (kh < 3) ? *(const f32x4*)(xp + 4) : onec;
        }
        __builtin_amdgcn_s_setprio(1);
        // x-part + own-h first (covers the partner-read latency)
        #pragma unroll
        for (int t4 = 0; t4 < 4; ++t4)
            acc[t4] = MFMA(wx[t4], xb, z4);
        #pragma unroll
        for (int t4 = 0; t4 < 4; ++t4)
            acc[t4] = MFMA(w2b[0][t4], hbO[0].v, acc[t4]);
        #pragma unroll
        for (int t4 = 0; t4 < 4; ++t4)
            acc[t4] = MFMA(w2b[1][t4], hbO[1].v, acc[t4]);
        // partner-h (slots 2,3 = partner pair by packing)
        #pragma unroll
        for (int t4 = 0; t4 < 4; ++t4)
            acc[t4] = MFMA(w2b[2][t4], hbP0, acc[t4]);
        #pragma unroll
        for (int t4 = 0; t4 < 4; ++t4)
            acc[t4] = MFMA(w2b[3][t4], hbP1, acc[t4]);
        __builtin_amdgcn_s_setprio(0);
        if (pf) xb = cvt8(na, nc);
        CVTALL;              // hbO now holds h_{t+1} own frags (register-only)
        XWRITE(cur ^ 1);     // publish for partner
        BAR;
        cur ^= 1;
    }

    // epilogue: p==0 computes out^T = W3^T.h_final^T + b3 (own frags in regs
    // = global kk 0,1; partner frags kk 2,3 from the final exchange)
    if (p == 0) {
        bf16x8 hbP0 = *(const bf16x8*)&Hs[cur][2][lane * 4];
        bf16x8 hbP1 = *(const bf16x8*)&Hs[cur][3][lane * 4];
        bf16x8 w3f[4];
        #pragma unroll
        for (int kk = 0; kk < 4; ++kk) w3f[kk] = *(const bf16x8*)(P + 80 + kk * 4);
        const float* bp = (const float*)(P + 96);
        f32x4 accO = {bp[0], bp[1], bp[2], bp[3]};
        accO = MFMA(w3f[0], hbO[0].v, accO);
        accO = MFMA(w3f[1], hbO[1].v, accO);
        accO = MFMA(w3f[2], hbP0,     accO);
        accO = MFMA(w3f[3], hbP1,     accO);
        float* op = out + (size_t)(r0 + lr) * 10 + kh * 4;
        #pragma unroll
        for (int j = 0; j < 4; ++j)
            if (kh * 4 + j < 10) op[j] = accO[j];
    }

#undef CVT
#undef CVTALL
#undef XWRITE
#undef BAR
}

extern "C" void kernel_launch(void* const* d_in, const int* in_sizes, int n_in,
                              void* d_out, int out_size, void* d_ws, size_t ws_size,
                              hipStream_t stream) {
    const float* x  = (const float*)d_in[0];
    const float* W1 = (const float*)d_in[1];
    const float* b1 = (const float*)d_in[2];
    const float* W2 = (const float*)d_in[3];
    const float* b2 = (const float*)d_in[4];
    const float* W3 = (const float*)d_in[5];
    const float* b3 = (const float*)d_in[6];
    unsigned int* ws = (unsigned int*)d_ws;   // 16896 dwords = 66 KiB

    pack1<<<31, 128, 0, stream>>>(W1, b1, W2, b2, W3, b3, ws);
    pack2<<<1, 64, 0, stream>>>(ws);
    rnn_kernel<<<BTOT / 16, 128, 0, stream>>>(x, ws, (float*)d_out);
}

// Round 29
// 71.560 us; speedup vs baseline: 4.9251x; 1.0980x over previous
//
#include <hip/hip_runtime.h>

#define BTOT 65536
#define TST  28
#define PACK_DW 180
// ws layout (dwords): [0 .. 11520) packed frags (64 lanes x 180)
//                     [11520 .. 15616) WxL: 32 x 128 f32 (rows 29..31 zeroed)
#define WXL_OFF (64 * PACK_DW)

typedef __attribute__((ext_vector_type(8))) short bf16x8;
typedef __attribute__((ext_vector_type(4))) float f32x4;

__device__ __forceinline__ unsigned int f2bf(float f) {
    unsigned u = __float_as_uint(f);
    u += 0x7fff + ((u >> 16) & 1);   // RNE
    return u >> 16;
}
__device__ __forceinline__ unsigned int pk2bf(float a, float b) {
    return f2bf(a) | (f2bf(b) << 16);
}
__device__ __forceinline__ bf16x8 cvt8(f32x4 a, f32x4 b) {
    union { unsigned int u[4]; bf16x8 v; } r;
    asm("v_cvt_pk_bf16_f32 %0, %1, %2" : "=v"(r.u[0]) : "v"(a[0]), "v"(a[1]));
    asm("v_cvt_pk_bf16_f32 %0, %1, %2" : "=v"(r.u[1]) : "v"(a[2]), "v"(a[3]));
    asm("v_cvt_pk_bf16_f32 %0, %1, %2" : "=v"(r.u[2]) : "v"(b[0]), "v"(b[1]));
    asm("v_cvt_pk_bf16_f32 %0, %1, %2" : "=v"(r.u[3]) : "v"(b[2]), "v"(b[3]));
    return r.v;
}

// HIDDEN-UNIT PERMUTATION sigma: B-frag slot (kh,kk,jd,b) consumes logical
// unit s = kk*32 + (jd>>1)*16 + kh*4 + (jd&1)*2 + b. With W2b/W3 input-rows
// packed by sigma, the cvt_pk dwords of acc tiles (2kk,2kk+1) ARE hb[kk] at
// the same lane -> h feedback is register-only (zero LDS). Verified r23:
// 71.9us, absmax 1.95e-3 — the session's best kernel (restored here).

// pack1: blocks 0..28 compute WxL row k (Wx = W1@W2a; row 28 = b2 + b1@W2a, hit
// by x-frag element k=28 := 1.0; block 28 zeroes rows 29..31). Block 29 packs
// W2b A-frags with sigma on the input-row index; block 30 packs W3 frags
// (sigma on rows) + b3 D-init.
// Per-lane dword layout: [0..128) w2b(kk,t8) | [128..160) wx(t8)
//                        [160..176) w3(kk)   | [176..180) b3 (f32, D rows)
__global__ void pack1(const float* __restrict__ W1, const float* __restrict__ b1,
                      const float* __restrict__ W2, const float* __restrict__ b2,
                      const float* __restrict__ W3, const float* __restrict__ b3,
                      unsigned int* __restrict__ ws) {
    float* WxL = (float*)(ws + WXL_OFF);
    const int bid = blockIdx.x, tid = threadIdx.x;
    if (bid < 29) {
        const int k = bid, n = tid;   // 128 threads
        float s = 0.f;
        if (k < 28) {
            for (int m = 0; m < 128; ++m) s += W1[k * 128 + m] * W2[m * 128 + n];
        } else {
            s = b2[n];
            for (int m = 0; m < 128; ++m) s += b1[m] * W2[m * 128 + n];
        }
        WxL[k * 128 + n] = s;
        if (k == 28) { WxL[29*128+n] = 0.f; WxL[30*128+n] = 0.f; WxL[31*128+n] = 0.f; }
    } else if (bid == 29) {
        if (tid < 64) {
            const int lr = tid & 15, kh = tid >> 4;
            unsigned int* P = ws + tid * PACK_DW;
            for (int kk = 0; kk < 4; ++kk)
                for (int t8 = 0; t8 < 8; ++t8)
                    for (int jd = 0; jd < 4; ++jd) {
                        const int s = kk * 32 + (jd >> 1) * 16 + kh * 4 + (jd & 1) * 2;
                        const int n = t8 * 16 + lr;
                        P[(kk * 8 + t8) * 4 + jd] =
                            pk2bf(W2[(128 + s) * 128 + n], W2[(129 + s) * 128 + n]);
                    }
        }
    } else {
        if (tid < 64) {
            const int lr = tid & 15, kh = tid >> 4;
            unsigned int* P = ws + tid * PACK_DW;
            for (int kk = 0; kk < 4; ++kk)
                for (int jd = 0; jd < 4; ++jd) {
                    const int s = kk * 32 + (jd >> 1) * 16 + kh * 4 + (jd & 1) * 2;
                    float lo = (lr < 10) ? W3[s * 10 + lr] : 0.f;
                    float hi = (lr < 10) ? W3[(s + 1) * 10 + lr] : 0.f;
                    P[160 + kk * 4 + jd] = pk2bf(lo, hi);
                }
            for (int j = 0; j < 4; ++j) {
                const int o = kh * 4 + j;
                P[176 + j] = __float_as_uint((o < 10) ? b3[o] : 0.f);
            }
        }
    }
}

// pack2: Wx A-frags (x's k-dimension — sigma does not apply).
__global__ void pack2(unsigned int* __restrict__ ws) {
    const int tid = threadIdx.x;
    if (tid < 64) {
        const float* WxL = (const float*)(ws + WXL_OFF);
        const int lr = tid & 15, kh = tid >> 4;
        unsigned int* P = ws + tid * PACK_DW;
        for (int t8 = 0; t8 < 8; ++t8)
            for (int jd = 0; jd < 4; ++jd) {
                const int k = kh * 8 + jd * 2, n = t8 * 16 + lr;
                P[128 + t8 * 4 + jd] = pk2bf(WxL[k * 128 + n], WxL[(k + 1) * 128 + n]);
            }
    }
}

// ZERO-LDS recurrence (r23, session best = 71.9us): 1 wave / 16 batch rows /
// all 128 n. h lives entirely in registers — sigma-packed weights make the
// cvt_pk outputs of acc tiles (2kk,2kk+1) directly equal to hb[kk]. Per step:
// 40 MFMA + 32 fmax + 16 cvt_pk. No DS ops, no barriers.
// Structural ceiling (measured): MFMA pipe floor 35us (19.4 cyc/MFMA, m06);
// register-resident weights cap residency at 2 waves/SIMD; in-order wave
// issue leaves ~50% pipe idle -> 38.5 cyc/slot -> ~72us. All software levers
// on that gap tested and nulled (r8-r28).
__global__ __launch_bounds__(64, 2) void rnn_kernel(
    const float* __restrict__ x, const unsigned int* __restrict__ wsPack,
    float* __restrict__ out)
{
    const int lane = threadIdx.x;
    const int lr = lane & 15, kh = lane >> 4;
    const int r0 = blockIdx.x * 16;

    const unsigned int* P = wsPack + lane * PACK_DW;
    bf16x8 w2b[4][8], wx[8];
    #pragma unroll
    for (int kk = 0; kk < 4; ++kk)
        #pragma unroll
        for (int t8 = 0; t8 < 8; ++t8)
            w2b[kk][t8] = *(const bf16x8*)(P + (kk * 8 + t8) * 4);
    #pragma unroll
    for (int t8 = 0; t8 < 8; ++t8) wx[t8] = *(const bf16x8*)(P + 128 + t8 * 4);

    // x B-frag: lane (kh,lr) covers k = 8kh + j of x[r0+lr][28t + k];
    // kh==3 upper half = {1.0 (k=28 bias hook), 0, 0, 0} — Wx rows 29..31 zero.
    const f32x4 onec = {1.f, 0.f, 0.f, 0.f};
    const float* xr = x + (size_t)(r0 + lr) * 784 + 8 * kh;
    f32x4 xa = *(const f32x4*)xr;
    f32x4 xc = (kh < 3) ? *(const f32x4*)(xr + 4) : onec;
    bf16x8 xb = cvt8(xa, xc);
    const f32x4 z4 = {0.f, 0.f, 0.f, 0.f};

    f32x4 acc[8];
    union HF { unsigned int u[4]; bf16x8 v; } hb[4];
    f32x4 na, nc;

// relu + pack acc[T8] -> the two dwords of hb[T8>>1] at offset (T8&1)*2.
// All indices compile-time -> stays in registers (SROA).
#define CVT(T8) do {                                                        \
        f32x4 v = acc[T8];                                                  \
        v[0] = fmaxf(v[0], 0.f); v[1] = fmaxf(v[1], 0.f);                   \
        v[2] = fmaxf(v[2], 0.f); v[3] = fmaxf(v[3], 0.f);                   \
        unsigned lo, hi;                                                    \
        asm("v_cvt_pk_bf16_f32 %0, %1, %2" : "=v"(lo) : "v"(v[0]), "v"(v[1])); \
        asm("v_cvt_pk_bf16_f32 %0, %1, %2" : "=v"(hi) : "v"(v[2]), "v"(v[3])); \
        hb[(T8) >> 1].u[((T8) & 1) * 2]     = lo;                           \
        hb[(T8) >> 1].u[((T8) & 1) * 2 + 1] = hi;                           \
    } while (0)
#define CVTALL  CVT(0); CVT(1); CVT(2); CVT(3); CVT(4); CVT(5); CVT(6); CVT(7)

    // ---- step 0: h0 == 0, so only the x part (exact) ----
    {
        const float* xp = xr + 28;
        na = *(const f32x4*)xp;
        nc = (kh < 3) ? *(const f32x4*)(xp + 4) : onec;
        __builtin_amdgcn_s_setprio(1);
        #pragma unroll
        for (int t8 = 0; t8 < 8; ++t8)
            acc[t8] = __builtin_amdgcn_mfma_f32_16x16x32_bf16(wx[t8], xb, z4, 0, 0, 0);
        __builtin_amdgcn_s_setprio(0);
        xb = cvt8(na, nc);
        CVTALL;
    }

    // ---- steps 1..27 ----
    #pragma unroll 2
    for (int t = 1; t < TST; ++t) {
        const bool pf = (t + 1 < TST);
        if (pf) {
            const float* xp = xr + (t + 1) * 28;
            na = *(const f32x4*)xp;
            nc = (kh < 3) ? *(const f32x4*)(xp + 4) : onec;
        }
        __builtin_amdgcn_s_setprio(1);
        #pragma unroll
        for (int t8 = 0; t8 < 8; ++t8)
            acc[t8] = __builtin_amdgcn_mfma_f32_16x16x32_bf16(wx[t8], xb, z4, 0, 0, 0);
        #pragma unroll
        for (int kk = 0; kk < 4; ++kk)
            #pragma unroll
            for (int t8 = 0; t8 < 8; ++t8)
                acc[t8] = __builtin_amdgcn_mfma_f32_16x16x32_bf16(w2b[kk][t8], hb[kk].v, acc[t8], 0, 0, 0);
        __builtin_amdgcn_s_setprio(0);
        if (pf) xb = cvt8(na, nc);
        CVTALL;   // registers ARE next step's B-frags (sigma packing)
    }

    // epilogue: out^T = W3^T . h_final^T + b3 — hb holds h_final already
    bf16x8 w3f[4];
    #pragma unroll
    for (int kk = 0; kk < 4; ++kk) w3f[kk] = *(const bf16x8*)(P + 160 + kk * 4);
    const float* bp = (const float*)(P + 176);
    f32x4 accO = {bp[0], bp[1], bp[2], bp[3]};
    #pragma unroll
    for (int kk = 0; kk < 4; ++kk)
        accO = __builtin_amdgcn_mfma_f32_16x16x32_bf16(w3f[kk], hb[kk].v, accO, 0, 0, 0);
    float* op = out + (size_t)(r0 + lr) * 10 + kh * 4;
    #pragma unroll
    for (int j = 0; j < 4; ++j)
        if (kh * 4 + j < 10) op[j] = accO[j];

#undef CVT
#undef CVTALL
}

extern "C" void kernel_launch(void* const* d_in, const int* in_sizes, int n_in,
                              void* d_out, int out_size, void* d_ws, size_t ws_size,
                              hipStream_t stream) {
    const float* x  = (const float*)d_in[0];
    const float* W1 = (const float*)d_in[1];
    const float* b1 = (const float*)d_in[2];
    const float* W2 = (const float*)d_in[3];
    const float* b2 = (const float*)d_in[4];
    const float* W3 = (const float*)d_in[5];
    const float* b3 = (const float*)d_in[6];
    unsigned int* ws = (unsigned int*)d_ws;   // 15616 dwords = 61 KiB

    pack1<<<31, 128, 0, stream>>>(W1, b1, W2, b2, W3, b3, ws);
    pack2<<<1, 64, 0, stream>>>(ws);
    rnn_kernel<<<BTOT / 16, 64, 0, stream>>>(x, ws, (float*)d_out);
}